// Round 14
// baseline (351.060 us; speedup 1.0000x reference)
//
#include <hip/hip_runtime.h>
#include <hip/hip_fp16.h>
#include <math.h>

#define NUM_USERS 100000
#define NUM_ITEMS 50000
#define N_NODES   150000   // NUM_USERS + NUM_ITEMS
#define N_EDGES   2400000
#define HALF_E    (N_EDGES / 2)
#define EMB       64
#define BATCH     4096
#define TAU        0.2f
#define SSL_LAMBDA 0.1f
#define REG_LAMBDA 1e-4f

// ---- binned CSR build (coarse 512-row buckets) ----
#define NB        293           // 293*512 = 150016 >= N_NODES
#define BROWS     512
#define CAP       13632         // item-bucket mean 12288 + 12 sigma
#define BINA_BLK  512
#define PER_BLK   ((HALF_E + BINA_BLK - 1) / BINA_BLK)   // 2344 edge-pairs
#define EBUF_CAP  (2 * PER_BLK)                          // 4688 records (37.5 KB)
#define CAST_BLK  2344          // cast role blocks (1024 thr: 2.4M elems)
#define JSPLIT    16            // ssl j-partials

// ---- spmm geometry: 8 lanes per row, 32 rows per 256-thr block ----
#define SROWS     32
#define SLDS      2048          // staged colval entries (16 KB LDS)

// ---------- helpers ----------
__device__ __forceinline__ float wave_sum(float v) {
    #pragma unroll
    for (int m = 1; m < 64; m <<= 1) v += __shfl_xor(v, m, 64);
    return v;
}
__device__ __forceinline__ int wave_sum_i(int v) {
    #pragma unroll
    for (int m = 1; m < 64; m <<= 1) v += __shfl_xor(v, m, 64);
    return v;
}
__device__ __forceinline__ __half2 bits2h2(int b) {
    union { int i; __half2 h; } u; u.i = b; return u.h;
}
__device__ __forceinline__ int h22bits(__half2 h) {
    union { int i; __half2 h; } u; u.h = h; return u.i;
}
__device__ __forceinline__ float h2f(unsigned short s) {
    union { unsigned short s; __half h; } u; u.s = s; return __half2float(u.h);
}
__device__ __forceinline__ unsigned short f2h_bits(float x) {
    union { __half h; unsigned short s; } u; u.h = __float2half_rn(x); return u.s;
}
typedef _Float16 half8 __attribute__((ext_vector_type(8)));
typedef float f32x4 __attribute__((ext_vector_type(4)));

// ================= prep: fused cast + edge binning, 1024-thread blocks =====
// R10-proven structure; NEW: fire-and-forget per-row global counts (rowcnt)
// produced during the hist loop, so bin_sort can skip its counting pass.
__global__ __launch_bounds__(1024) void prep(
        const int* __restrict__ row, const int* __restrict__ col,
        const float* __restrict__ val,
        int* __restrict__ bucket_cursor, int* __restrict__ rowcnt,
        int2* __restrict__ arena,
        const float4* __restrict__ uw4, const float4* __restrict__ iw4,
        uint2* __restrict__ h) {
    __shared__ int hist[NB];      // counts -> local running cursor
    __shared__ int lbase[NB];     // local exclusive base
    __shared__ int delta[NB];     // arena_run_start - lbase
    __shared__ int sm[256];
    __shared__ int2 ebuf[EBUF_CAP];
    const int t = threadIdx.x;

    if (blockIdx.x >= BINA_BLK) {
        // ---- cast role (1024 threads, one-shot) ----
        size_t i = (size_t)(blockIdx.x - BINA_BLK) * 1024 + t;
        const size_t tot = (size_t)N_NODES * EMB / 4;
        if (i >= tot) return;
        const size_t nu = (size_t)NUM_USERS * EMB / 4;
        float4 v = (i < nu) ? uw4[i] : iw4[i - nu];
        h[i] = make_uint2(h22bits(__floats2half2_rn(v.x, v.y)),
                          h22bits(__floats2half2_rn(v.z, v.w)));
        return;
    }

    // ---- scatter role ----
    for (int k = t; k < NB; k += 1024) hist[k] = 0;
    __syncthreads();
    const int beg = blockIdx.x * PER_BLK;
    const int end = min(beg + PER_BLK, HALF_E);
    for (int e = beg + t; e < end; e += 1024) {
        int r = row[e], c = col[e];
        atomicAdd(&hist[r >> 9], 1);
        atomicAdd(&hist[c >> 9], 1);
        atomicAdd(&rowcnt[r], 1);      // fire-and-forget (no return use)
        atomicAdd(&rowcnt[c], 1);
    }
    __syncthreads();
    int v0 = 0, v1 = 0, s = 0;
    if (t < 256) {
        v0 = (2 * t < NB) ? hist[2 * t] : 0;
        v1 = (2 * t + 1 < NB) ? hist[2 * t + 1] : 0;
        s = v0 + v1;
        sm[t] = s;
    }
    __syncthreads();
    for (int m = 1; m < 256; m <<= 1) {
        int y = (t < 256 && t >= m) ? sm[t - m] : 0;
        __syncthreads();
        if (t < 256) sm[t] += y;
        __syncthreads();
    }
    if (t < 256) {
        int excl = sm[t] - s;
        if (2 * t < NB) lbase[2 * t] = excl;
        if (2 * t + 1 < NB) lbase[2 * t + 1] = excl + v0;
    }
    __syncthreads();
    for (int k = t; k < NB; k += 1024) {
        int cnt = hist[k];
        int gb = cnt ? atomicAdd(&bucket_cursor[k], cnt) : 0;
        delta[k] = (k * CAP + gb) - lbase[k];
    }
    __syncthreads();
    for (int k = t; k < NB; k += 1024) hist[k] = lbase[k];  // running cursor
    __syncthreads();
    for (int e = beg + t; e < end; e += 1024) {
        int r = row[e], c = col[e];
        unsigned short h1 = f2h_bits(val[e]);
        unsigned short h2v = f2h_bits(val[e + HALF_E]);
        int b1 = r >> 9, b2 = c >> 9;
        int p1 = atomicAdd(&hist[b1], 1);
        int p2 = atomicAdd(&hist[b2], 1);
        ebuf[p1] = make_int2(c | ((r & 511) << 18), (b1 << 16) | h1);
        ebuf[p2] = make_int2(r | ((c & 511) << 18), (b2 << 16) | h2v);
    }
    __syncthreads();
    const int count = 2 * (end - beg);
    for (int k = t; k < count; k += 1024) {
        int2 rec = ebuf[k];
        int b = rec.y >> 16;
        arena[k + delta[b]] = rec;
    }
}

// ================= per-bucket counting sort -> CSR + rowptr =======
// Pass-1 (arena counting) DELETED: rcnt loaded directly from prep's rowcnt.
// Single arena pass (scatter). Overflow (>CAP, ~12-sigma) guarded by a
// range-zero so dropped slots read as 0-weight edges.
__global__ __launch_bounds__(1024) void bin_sort(
        const int* __restrict__ bucket_cursor, const int* __restrict__ rowcnt,
        const int2* __restrict__ arena,
        int* __restrict__ rowptr, int2* __restrict__ colval) {
    __shared__ int rcnt[BROWS];
    __shared__ int sm[256];
    __shared__ int wred[16];
    const int bin = blockIdx.x;
    const int t = threadIdx.x;
    const int total = bucket_cursor[bin];
    const int count = min(total, CAP);
    int part = (t < NB && t < bin) ? bucket_cursor[t] : 0;
    part = wave_sum_i(part);
    if ((t & 63) == 0) wred[t >> 6] = part;
    if (t < BROWS) {
        int gr = bin * BROWS + t;
        rcnt[t] = (gr < N_NODES) ? rowcnt[gr] : 0;
    }
    if (bin == 0 && t == 0) rowptr[N_NODES] = N_EDGES;
    __syncthreads();
    int gbase = 0;
    #pragma unroll
    for (int w = 0; w < 16; w++) gbase += wred[w];

    int v0 = 0, v1 = 0, s = 0;
    if (t < 256) {
        v0 = rcnt[2 * t]; v1 = rcnt[2 * t + 1];
        s = v0 + v1;
        sm[t] = s;
    }
    __syncthreads();
    for (int m = 1; m < 256; m <<= 1) {
        int y = (t < 256 && t >= m) ? sm[t - m] : 0;
        __syncthreads();
        if (t < 256) sm[t] += y;
        __syncthreads();
    }
    if (t < 256) {
        int excl = sm[t] - s;
        rcnt[2 * t] = excl;
        rcnt[2 * t + 1] = excl + v0;
        int r0 = bin * BROWS + 2 * t;
        if (r0 < N_NODES) rowptr[r0] = gbase + excl;
        if (r0 + 1 < N_NODES) rowptr[r0 + 1] = gbase + excl + v0;
    }
    __syncthreads();
    if (total > CAP) {   // safety net, effectively never taken
        for (int i = t; i < total; i += 1024)
            colval[gbase + i] = make_int2(0, 0);
        __syncthreads();
    }
    for (int i = t; i < count; i += 1024) {
        int2 rec = arena[bin * CAP + i];
        int pos = atomicAdd(&rcnt[(rec.x >> 18) & 511], 1);
        unsigned int hv = (unsigned int)rec.y & 0xFFFFu;
        colval[gbase + pos] = make_int2(rec.x & 0x3FFFF, (int)(hv * 0x10001u));
    }
}

// ================= gather SpMM (fp16), 8 lanes/row, LDS-staged colval ======
__device__ __forceinline__ void fma_slice(__half2& ac0, __half2& ac1,
        __half2& ac2, __half2& ac3, int cy, uint4 x) {
    __half2 vv = bits2h2(cy);
    ac0 = __hfma2(vv, bits2h2((int)x.x), ac0);
    ac1 = __hfma2(vv, bits2h2((int)x.y), ac1);
    ac2 = __hfma2(vv, bits2h2((int)x.z), ac2);
    ac3 = __hfma2(vv, bits2h2((int)x.w), ac3);
}

template <bool USE_LDS>
__device__ __forceinline__ void ldk(int kk, int kel, int l, int beg0,
        const int2* __restrict__ gcv, const int2* lcv,
        const uint4* __restrict__ tab, int2& cv, uint4& xv) {
    int kc = min(kk, kel);
    cv = USE_LDS ? lcv[kc - beg0] : gcv[kc];
    if (kk > kel) cv.y = 0;
    xv = tab[(((unsigned)cv.x) << 3) + l];
}

// 4-deep pipelined accumulation (R10 best-measured; depth-6 was null in R12).
template <bool USE_LDS>
__device__ __forceinline__ void row_accum(
        int lo, int hi, int l, int beg0,
        const int2* __restrict__ gcv, const int2* lcv,
        const uint4* __restrict__ tab,
        __half2& ac0, __half2& ac1, __half2& ac2, __half2& ac3) {
    if (hi <= lo) return;
    const int kel = hi - 1;
    int2 c0, c1, c2, c3; uint4 x0, x1, x2, x3;
    ldk<USE_LDS>(lo,     kel, l, beg0, gcv, lcv, tab, c0, x0);
    ldk<USE_LDS>(lo + 1, kel, l, beg0, gcv, lcv, tab, c1, x1);
    ldk<USE_LDS>(lo + 2, kel, l, beg0, gcv, lcv, tab, c2, x2);
    ldk<USE_LDS>(lo + 3, kel, l, beg0, gcv, lcv, tab, c3, x3);
    for (int kk = lo + 4; kk < hi; kk += 4) {
        int2 d0, d1, d2, d3; uint4 y0, y1, y2, y3;
        ldk<USE_LDS>(kk,     kel, l, beg0, gcv, lcv, tab, d0, y0);
        ldk<USE_LDS>(kk + 1, kel, l, beg0, gcv, lcv, tab, d1, y1);
        ldk<USE_LDS>(kk + 2, kel, l, beg0, gcv, lcv, tab, d2, y2);
        ldk<USE_LDS>(kk + 3, kel, l, beg0, gcv, lcv, tab, d3, y3);
        fma_slice(ac0, ac1, ac2, ac3, c0.y, x0);
        fma_slice(ac0, ac1, ac2, ac3, c1.y, x1);
        fma_slice(ac0, ac1, ac2, ac3, c2.y, x2);
        fma_slice(ac0, ac1, ac2, ac3, c3.y, x3);
        c0 = d0; x0 = y0; c1 = d1; x1 = y1;
        c2 = d2; x2 = y2; c3 = d3; x3 = y3;
    }
    fma_slice(ac0, ac1, ac2, ac3, c0.y, x0);
    fma_slice(ac0, ac1, ac2, ac3, c1.y, x1);
    fma_slice(ac0, ac1, ac2, ac3, c2.y, x2);
    fma_slice(ac0, ac1, ac2, ac3, c3.y, x3);
}

__global__ __launch_bounds__(256) void spmm_csr(
        const int* __restrict__ rowptr, const int2* __restrict__ colval,
        const unsigned short* __restrict__ h_cur, unsigned short* __restrict__ h_next) {
    __shared__ int2 ecv[SLDS];
    const int t = threadIdx.x;
    const int g = t >> 3;            // row group 0..31
    const int l = t & 7;             // uint4 slice within row
    const int base = blockIdx.x * SROWS;
    const int r = base + g;
    int lo = 0, hi = 0;
    if (r < N_NODES) { lo = rowptr[r]; hi = rowptr[r + 1]; }
    const int beg0 = rowptr[base];
    const int end0 = rowptr[min(base + SROWS, N_NODES)];
    const int nE = end0 - beg0;
    const bool use_lds = (nE <= SLDS);
    if (use_lds)
        for (int i = t; i < nE; i += 256) ecv[i] = colval[beg0 + i];
    __syncthreads();
    __half2 ac0 = __float2half2_rn(0.0f), ac1 = ac0, ac2 = ac0, ac3 = ac0;
    const uint4* tab = (const uint4*)h_cur;
    if (r < N_NODES) {
        if (use_lds)
            row_accum<true>(lo, hi, l, beg0, colval, ecv, tab, ac0, ac1, ac2, ac3);
        else
            row_accum<false>(lo, hi, l, beg0, colval, ecv, tab, ac0, ac1, ac2, ac3);
        ((uint4*)(h_next + (size_t)r * EMB))[l] =
            make_uint4((unsigned)h22bits(ac0), (unsigned)h22bits(ac1),
                       (unsigned)h22bits(ac2), (unsigned)h22bits(ac3));
    }
}

// ---- gather one row (spmm_sel inner loop, exact arithmetic), all-lane result
__device__ __forceinline__ void gather_row(
        const int* __restrict__ rowptr, const int2* __restrict__ colval,
        const unsigned short* __restrict__ h_cur, int r, int g, int l,
        int& ra0, int& ra1, int& ra2, int& ra3) {
    const int beg = rowptr[r], end = rowptr[r + 1];
    __half2 ac0 = __float2half2_rn(0.0f), ac1 = ac0, ac2 = ac0, ac3 = ac0;
    int e = beg + g;
    if (e < end) {
        int2 cv = colval[e];
        uint4 x = ((const uint4*)(h_cur + (size_t)cv.x * EMB))[l];
        e += 8;
        if (e < end) {
            int2 cv2 = colval[e];
            uint4 x2 = ((const uint4*)(h_cur + (size_t)cv2.x * EMB))[l];
            for (e += 8; e < end; e += 8) {
                int2 cv3 = colval[e];
                uint4 x3 = ((const uint4*)(h_cur + (size_t)cv3.x * EMB))[l];
                fma_slice(ac0, ac1, ac2, ac3, cv.y, x);
                cv = cv2; x = x2; cv2 = cv3; x2 = x3;
            }
            fma_slice(ac0, ac1, ac2, ac3, cv.y, x);
            cv = cv2; x = x2;
        }
        fma_slice(ac0, ac1, ac2, ac3, cv.y, x);
    }
    int a0 = h22bits(ac0), a1 = h22bits(ac1), a2 = h22bits(ac2), a3 = h22bits(ac3);
    #pragma unroll
    for (int m = 8; m < 64; m <<= 1) {
        a0 = h22bits(__hadd2(bits2h2(a0), bits2h2(__shfl_xor(a0, m, 64))));
        a1 = h22bits(__hadd2(bits2h2(a1), bits2h2(__shfl_xor(a1, m, 64))));
        a2 = h22bits(__hadd2(bits2h2(a2), bits2h2(__shfl_xor(a2, m, 64))));
        a3 = h22bits(__hadd2(bits2h2(a3), bits2h2(__shfl_xor(a3, m, 64))));
    }
    ra0 = a0; ra1 = a1; ra2 = a2; ra3 = a3;
}

// store layer3 row + e2 self row (f32) into LDS slice [64]
__device__ __forceinline__ void store_row(float* dst,
        const unsigned short* __restrict__ h_cur, int r, int l,
        int a0, int a1, int a2, int a3) {
    uint4 hx = ((const uint4*)(h_cur + (size_t)r * EMB))[l];
    float2 f0 = __half22float2(bits2h2(a0));
    float2 f1 = __half22float2(bits2h2(a1));
    float2 f2 = __half22float2(bits2h2(a2));
    float2 f3 = __half22float2(bits2h2(a3));
    float2 s0 = __half22float2(bits2h2((int)hx.x));
    float2 s1 = __half22float2(bits2h2((int)hx.y));
    float2 s2 = __half22float2(bits2h2((int)hx.z));
    float2 s3 = __half22float2(bits2h2((int)hx.w));
    float* d = dst + 8 * l;
    d[0] = f0.x + s0.x; d[1] = f0.y + s0.y; d[2] = f1.x + s1.x; d[3] = f1.y + s1.y;
    d[4] = f2.x + s2.x; d[5] = f2.y + s2.y; d[6] = f3.x + s3.x; d[7] = f3.y + s3.y;
}

// ======== sel_loss: layer-3 selective SpMM fused with the batch losses ======
__global__ __launch_bounds__(256) void sel_loss(
        const int* __restrict__ rowptr, const int2* __restrict__ colval,
        const int* __restrict__ user, const int* __restrict__ pos,
        const int* __restrict__ neg,
        const float* __restrict__ uw, const float* __restrict__ iw,
        const unsigned short* __restrict__ hA,   // layer-2 table (gather + self)
        const unsigned short* __restrict__ hB,   // layer-1 table (e1 term)
        unsigned short* __restrict__ unh, unsigned short* __restrict__ pnh,
        float* __restrict__ diag,
        float* __restrict__ pbpr, float* __restrict__ preg) {
    __shared__ float srow[3][4][64];
    __shared__ float lb[4], lr[4];
    const int t = threadIdx.x;
    const int lane = t & 63;
    const int w = t >> 6;
    const int g = lane >> 3, l = lane & 7;
    const int b = blockIdx.x * 4 + w;
    const int nu = user[b], np = pos[b], ng = neg[b];
    int a0, a1, a2, a3;
    gather_row(rowptr, colval, hA, nu, g, l, a0, a1, a2, a3);
    if (g == 0) store_row(&srow[0][w][0], hA, nu, l, a0, a1, a2, a3);
    gather_row(rowptr, colval, hA, NUM_USERS + np, g, l, a0, a1, a2, a3);
    if (g == 0) store_row(&srow[1][w][0], hA, NUM_USERS + np, l, a0, a1, a2, a3);
    gather_row(rowptr, colval, hA, NUM_USERS + ng, g, l, a0, a1, a2, a3);
    if (g == 0) store_row(&srow[2][w][0], hA, NUM_USERS + ng, l, a0, a1, a2, a3);
    __syncthreads();
    const float inv4 = 0.25f;  // / (GCN_LAYERS + 1)
    float u = (uw[(size_t)nu * EMB + lane]
             + h2f(hB[(size_t)nu * EMB + lane])
             + srow[0][w][lane]) * inv4;
    float p = (iw[(size_t)np * EMB + lane]
             + h2f(hB[(size_t)(NUM_USERS + np) * EMB + lane])
             + srow[1][w][lane]) * inv4;
    float n = (iw[(size_t)ng * EMB + lane]
             + h2f(hB[(size_t)(NUM_USERS + ng) * EMB + lane])
             + srow[2][w][lane]) * inv4;
    float pos_s = wave_sum(u * p);
    float neg_s = wave_sum(u * n);
    float uu = wave_sum(u * u);
    float pp = wave_sum(p * p);
    float nn = wave_sum(n * n);
    float ru = rsqrtf(uu), rp = rsqrtf(pp);
    unh[(size_t)b * EMB + lane] = f2h_bits(u * ru);
    pnh[(size_t)b * EMB + lane] = f2h_bits(p * rp);
    if (lane == 0) {
        diag[b] = pos_s * ru * rp * (1.0f / TAU);
        float d = pos_s - neg_s;
        float tt = -d;
        lb[w] = fmaxf(tt, 0.0f) + log1pf(expf(-fabsf(tt)));  // softplus(-d)
        lr[w] = uu + pp + nn;
    }
    __syncthreads();
    if (t == 0) {
        pbpr[blockIdx.x] = lb[0] + lb[1] + lb[2] + lb[3];
        preg[blockIdx.x] = lr[0] + lr[1] + lr[2] + lr[3];
    }
}

// ================= SSL via MFMA (16x16x32 f16, fp32 accum) =================
__global__ __launch_bounds__(256) void ssl_mfma(
        const unsigned short* __restrict__ unh, const unsigned short* __restrict__ pnh,
        float* __restrict__ rowsum_p) {
    const int t = threadIdx.x;
    const int lane = t & 63;
    const int idx = lane & 15, quad = lane >> 4;
    int job = blockIdx.x * 4 + (t >> 6);     // 4096 jobs = 256 it x 16 js
    int it = job & 255, js = job >> 8;
    const int i0 = it * 16;
    half8 a0 = *(const half8*)(unh + (size_t)(i0 + idx) * EMB + quad * 8);
    half8 a1 = *(const half8*)(unh + (size_t)(i0 + idx) * EMB + 32 + quad * 8);
    float rs0 = 0.0f, rs1 = 0.0f, rs2 = 0.0f, rs3 = 0.0f;
    const int NJT = BATCH / JSPLIT / 16;     // 16
    for (int jt = 0; jt < NJT; jt++) {
        int j0 = js * (BATCH / JSPLIT) + jt * 16;
        half8 b0 = *(const half8*)(pnh + (size_t)(j0 + idx) * EMB + quad * 8);
        half8 b1 = *(const half8*)(pnh + (size_t)(j0 + idx) * EMB + 32 + quad * 8);
        f32x4 c = {0.0f, 0.0f, 0.0f, 0.0f};
        c = __builtin_amdgcn_mfma_f32_16x16x32_f16(a0, b0, c, 0, 0, 0);
        c = __builtin_amdgcn_mfma_f32_16x16x32_f16(a1, b1, c, 0, 0, 0);
        rs0 += __expf(c[0] * (1.0f / TAU));
        rs1 += __expf(c[1] * (1.0f / TAU));
        rs2 += __expf(c[2] * (1.0f / TAU));
        rs3 += __expf(c[3] * (1.0f / TAU));
    }
    #pragma unroll
    for (int m = 1; m < 16; m <<= 1) {
        rs0 += __shfl_xor(rs0, m, 64);
        rs1 += __shfl_xor(rs1, m, 64);
        rs2 += __shfl_xor(rs2, m, 64);
        rs3 += __shfl_xor(rs3, m, 64);
    }
    if (idx == 0) {
        float* dst = rowsum_p + (size_t)js * BATCH + i0 + quad * 4;
        dst[0] = rs0; dst[1] = rs1; dst[2] = rs2; dst[3] = rs3;
    }
}

// single block: reduce rowsum partials + ssl terms + bpr/reg partials -> loss
__global__ __launch_bounds__(256) void finalize(
        const float* __restrict__ rowsum_p, const float* __restrict__ diag,
        const float* __restrict__ pbpr, const float* __restrict__ preg,
        float* __restrict__ out) {
    __shared__ float red[3][4];
    const int t = threadIdx.x;
    float sb = 0.0f, sr = 0.0f, ss = 0.0f;
    for (int i = t; i < BATCH / 4; i += 256) { sb += pbpr[i]; sr += preg[i]; }
    for (int i = t; i < BATCH; i += 256) {
        float rs = 0.0f;
        #pragma unroll
        for (int j = 0; j < JSPLIT; j++) rs += rowsum_p[(size_t)j * BATCH + i];
        ss += logf(rs) - diag[i];
    }
    sb = wave_sum(sb); sr = wave_sum(sr); ss = wave_sum(ss);
    const int w = t >> 6;
    if ((t & 63) == 0) { red[0][w] = sb; red[1][w] = sr; red[2][w] = ss; }
    __syncthreads();
    if (t == 0) {
        float bpr_sum = red[0][0] + red[0][1] + red[0][2] + red[0][3];
        float reg_sum = red[1][0] + red[1][1] + red[1][2] + red[1][3];
        float ssl_sum = red[2][0] + red[2][1] + red[2][2] + red[2][3];
        float bpr = bpr_sum * (1.0f / BATCH);
        float reg = 0.5f * reg_sum * (1.0f / BATCH) * REG_LAMBDA;
        float ssl = ssl_sum * (1.0f / BATCH) * SSL_LAMBDA;
        out[0] = bpr + reg + ssl;
    }
}

extern "C" void kernel_launch(void* const* d_in, const int* in_sizes, int n_in,
                              void* d_out, int out_size, void* d_ws, size_t ws_size,
                              hipStream_t stream) {
    const int*   user    = (const int*)d_in[0];
    const int*   pos     = (const int*)d_in[1];
    const int*   neg     = (const int*)d_in[2];
    const int*   adj_row = (const int*)d_in[3];
    const int*   adj_col = (const int*)d_in[4];
    const float* adj_val = (const float*)d_in[5];
    const float* user_w  = (const float*)d_in[6];
    const float* item_w  = (const float*)d_in[7];
    float* out = (float*)d_out;

    // ---- workspace layout ----
    unsigned short* hA = (unsigned short*)d_ws;            // fp16 table (19.2 MB)
    unsigned short* hB = hA + (size_t)N_NODES * EMB;       // fp16 table (19.2 MB)
    float* buf1   = (float*)d_ws + (size_t)N_NODES * EMB;  // 38.4 MB arena region
    float* sel    = buf1 + (size_t)N_NODES * EMB;          // 3 MB: cursors+rowcnt
    unsigned short* unh = (unsigned short*)(sel + (size_t)3 * BATCH * EMB); // 512KB
    unsigned short* pnh = unh + (size_t)BATCH * EMB;       // 512 KB
    float* diag   = (float*)(pnh + (size_t)BATCH * EMB);   // 4096 f
    float* rowsum_p = diag + BATCH;                        // 16*4096 f
    float* pbpr   = rowsum_p + JSPLIT * BATCH;             // 1024 f
    float* preg   = pbpr + 1024;                           // 1024 f
    int*   rowptr = (int*)(preg + 1024);                   // 150016 i
    int*   pad0   = rowptr + 150016;                       // 1024 i (layout keep)
    int2*  colval = (int2*)(pad0 + 1024);                  // 2.4M int2 (19.2 MB)
    int2*  arena  = (int2*)buf1;  // NB*CAP int2 = 31.95 MB <= 38.4 MB region
    int*   bucket_cursor = (int*)sel;                      // 512 i
    int*   rowcnt = bucket_cursor + 512;                   // 150016 i

    // single memset zeroes bucket cursors + per-row counts (602 KB)
    (void)hipMemsetAsync(bucket_cursor, 0, (512 + 150016) * sizeof(int), stream);
    prep<<<BINA_BLK + CAST_BLK, dim3(1024), 0, stream>>>(adj_row, adj_col, adj_val,
                                                         bucket_cursor, rowcnt, arena,
                                                         (const float4*)user_w,
                                                         (const float4*)item_w,
                                                         (uint2*)hA);
    bin_sort<<<NB, dim3(1024), 0, stream>>>(bucket_cursor, rowcnt, arena,
                                            rowptr, colval);

    dim3 blk(256);
    // layers 1,2: full spmm (fp16 tables)
    spmm_csr<<<(N_NODES + SROWS - 1) / SROWS, blk, 0, stream>>>(rowptr, colval, hA, hB);
    spmm_csr<<<(N_NODES + SROWS - 1) / SROWS, blk, 0, stream>>>(rowptr, colval, hB, hA);

    // layer-3 selective spmm + e2 self + e0/e1 gathers + losses (fused)
    sel_loss<<<BATCH / 4, blk, 0, stream>>>(rowptr, colval, user, pos, neg,
                                            user_w, item_w, hA, hB,
                                            unh, pnh, diag, pbpr, preg);
    // ssl rowsums, then tiny finalize (kernel boundary = cheap global sync)
    ssl_mfma<<<BATCH * JSPLIT / 16 / 4, blk, 0, stream>>>(unh, pnh, rowsum_p);
    finalize<<<1, blk, 0, stream>>>(rowsum_p, diag, pbpr, preg, out);
}

// Round 15
// 267.881 us; speedup vs baseline: 1.3105x; 1.3105x over previous
//
#include <hip/hip_runtime.h>
#include <hip/hip_fp16.h>
#include <math.h>

#define NUM_USERS 100000
#define NUM_ITEMS 50000
#define N_NODES   150000   // NUM_USERS + NUM_ITEMS
#define N_EDGES   2400000
#define HALF_E    (N_EDGES / 2)
#define EMB       64
#define BATCH     4096
#define TAU        0.2f
#define SSL_LAMBDA 0.1f
#define REG_LAMBDA 1e-4f

// ---- binned CSR build (coarse 512-row buckets) ----
#define NB        293           // 293*512 = 150016 >= N_NODES
#define BROWS     512
#define CAP       13632         // item-bucket mean 12288 + 12 sigma
#define BINA_BLK  512
#define PER_BLK   ((HALF_E + BINA_BLK - 1) / BINA_BLK)   // 2344 edge-pairs
#define EBUF_CAP  (2 * PER_BLK)                          // 4688 records (37.5 KB)
#define CAST_BLK  2344          // cast role blocks (1024 thr: 2.4M elems)
#define JSPLIT    16            // ssl j-partials

// ---- spmm geometry: 8 lanes per row, 32 rows per 256-thr block ----
#define SROWS     32
#define SLDS      2048          // staged colval entries (16 KB LDS)

// ---------- helpers ----------
__device__ __forceinline__ float wave_sum(float v) {
    #pragma unroll
    for (int m = 1; m < 64; m <<= 1) v += __shfl_xor(v, m, 64);
    return v;
}
__device__ __forceinline__ int wave_sum_i(int v) {
    #pragma unroll
    for (int m = 1; m < 64; m <<= 1) v += __shfl_xor(v, m, 64);
    return v;
}
__device__ __forceinline__ __half2 bits2h2(int b) {
    union { int i; __half2 h; } u; u.i = b; return u.h;
}
__device__ __forceinline__ int h22bits(__half2 h) {
    union { int i; __half2 h; } u; u.h = h; return u.i;
}
__device__ __forceinline__ float h2f(unsigned short s) {
    union { unsigned short s; __half h; } u; u.s = s; return __half2float(u.h);
}
__device__ __forceinline__ unsigned short f2h_bits(float x) {
    union { __half h; unsigned short s; } u; u.h = __float2half_rn(x); return u.s;
}
typedef _Float16 half8 __attribute__((ext_vector_type(8)));
typedef float f32x4 __attribute__((ext_vector_type(4)));

// ================= prep: fused cast + edge binning, 1024-thread blocks =====
// (R10-proven best: 41 -> ~34 us via 4x intra-block parallelism; R13's
// global rowcnt atomics REVERTED: +74 MB write amplification, prep 117 us)
__global__ __launch_bounds__(1024) void prep(
        const int* __restrict__ row, const int* __restrict__ col,
        const float* __restrict__ val,
        int* __restrict__ bucket_cursor, int2* __restrict__ arena,
        const float4* __restrict__ uw4, const float4* __restrict__ iw4,
        uint2* __restrict__ h) {
    __shared__ int hist[NB];      // counts -> local running cursor
    __shared__ int lbase[NB];     // local exclusive base
    __shared__ int delta[NB];     // arena_run_start - lbase
    __shared__ int sm[256];
    __shared__ int2 ebuf[EBUF_CAP];
    const int t = threadIdx.x;

    if (blockIdx.x >= BINA_BLK) {
        // ---- cast role (1024 threads, one-shot) ----
        size_t i = (size_t)(blockIdx.x - BINA_BLK) * 1024 + t;
        const size_t tot = (size_t)N_NODES * EMB / 4;
        if (i >= tot) return;
        const size_t nu = (size_t)NUM_USERS * EMB / 4;
        float4 v = (i < nu) ? uw4[i] : iw4[i - nu];
        h[i] = make_uint2(h22bits(__floats2half2_rn(v.x, v.y)),
                          h22bits(__floats2half2_rn(v.z, v.w)));
        return;
    }

    // ---- scatter role ----
    for (int k = t; k < NB; k += 1024) hist[k] = 0;
    __syncthreads();
    const int beg = blockIdx.x * PER_BLK;
    const int end = min(beg + PER_BLK, HALF_E);
    for (int e = beg + t; e < end; e += 1024) {
        int r = row[e], c = col[e];
        atomicAdd(&hist[r >> 9], 1);
        atomicAdd(&hist[c >> 9], 1);
    }
    __syncthreads();
    int v0 = 0, v1 = 0, s = 0;
    if (t < 256) {
        v0 = (2 * t < NB) ? hist[2 * t] : 0;
        v1 = (2 * t + 1 < NB) ? hist[2 * t + 1] : 0;
        s = v0 + v1;
        sm[t] = s;
    }
    __syncthreads();
    for (int m = 1; m < 256; m <<= 1) {
        int y = (t < 256 && t >= m) ? sm[t - m] : 0;
        __syncthreads();
        if (t < 256) sm[t] += y;
        __syncthreads();
    }
    if (t < 256) {
        int excl = sm[t] - s;
        if (2 * t < NB) lbase[2 * t] = excl;
        if (2 * t + 1 < NB) lbase[2 * t + 1] = excl + v0;
    }
    __syncthreads();
    for (int k = t; k < NB; k += 1024) {
        int cnt = hist[k];
        int gb = cnt ? atomicAdd(&bucket_cursor[k], cnt) : 0;
        delta[k] = (k * CAP + gb) - lbase[k];
    }
    __syncthreads();
    for (int k = t; k < NB; k += 1024) hist[k] = lbase[k];  // running cursor
    __syncthreads();
    for (int e = beg + t; e < end; e += 1024) {
        int r = row[e], c = col[e];
        unsigned short h1 = f2h_bits(val[e]);
        unsigned short h2v = f2h_bits(val[e + HALF_E]);
        int b1 = r >> 9, b2 = c >> 9;
        int p1 = atomicAdd(&hist[b1], 1);
        int p2 = atomicAdd(&hist[b2], 1);
        ebuf[p1] = make_int2(c | ((r & 511) << 18), (b1 << 16) | h1);
        ebuf[p2] = make_int2(r | ((c & 511) << 18), (b2 << 16) | h2v);
    }
    __syncthreads();
    const int count = 2 * (end - beg);
    for (int k = t; k < count; k += 1024) {
        int2 rec = ebuf[k];
        int b = rec.y >> 16;
        arena[k + delta[b]] = rec;
    }
}

// ================= per-bucket counting sort -> CSR + rowptr =======
__global__ __launch_bounds__(1024) void bin_sort(
        const int* __restrict__ bucket_cursor,
        const int2* __restrict__ arena,
        int* __restrict__ rowptr, int2* __restrict__ colval) {
    __shared__ int rcnt[BROWS];
    __shared__ int sm[256];
    __shared__ int wred[16];
    const int bin = blockIdx.x;
    const int t = threadIdx.x;
    const int total = bucket_cursor[bin];
    const int count = min(total, CAP);
    int part = (t < NB && t < bin) ? bucket_cursor[t] : 0;
    part = wave_sum_i(part);
    if ((t & 63) == 0) wred[t >> 6] = part;
    if (t < BROWS) rcnt[t] = 0;
    if (bin == 0 && t == 0) rowptr[N_NODES] = N_EDGES;
    __syncthreads();
    int gbase = 0;
    #pragma unroll
    for (int w = 0; w < 16; w++) gbase += wred[w];

    for (int i = t; i < count; i += 1024) {
        int rx = arena[bin * CAP + i].x >> 18;
        atomicAdd(&rcnt[rx & 511], 1);
    }
    __syncthreads();
    int v0 = 0, v1 = 0, s = 0;
    if (t < 256) {
        v0 = rcnt[2 * t]; v1 = rcnt[2 * t + 1];
        s = v0 + v1;
        sm[t] = s;
    }
    __syncthreads();
    for (int m = 1; m < 256; m <<= 1) {
        int y = (t < 256 && t >= m) ? sm[t - m] : 0;
        __syncthreads();
        if (t < 256) sm[t] += y;
        __syncthreads();
    }
    if (t < 256) {
        int excl = sm[t] - s;
        rcnt[2 * t] = excl;
        rcnt[2 * t + 1] = excl + v0;
        int r0 = bin * BROWS + 2 * t;
        if (r0 < N_NODES) rowptr[r0] = gbase + excl;
        if (r0 + 1 < N_NODES) rowptr[r0 + 1] = gbase + excl + v0;
    }
    __syncthreads();
    for (int i = t; i < count; i += 1024) {
        int2 rec = arena[bin * CAP + i];
        int pos = atomicAdd(&rcnt[(rec.x >> 18) & 511], 1);
        unsigned int hv = (unsigned int)rec.y & 0xFFFFu;
        colval[gbase + pos] = make_int2(rec.x & 0x3FFFF, (int)(hv * 0x10001u));
    }
    for (int i = count + t; i < total; i += 1024)
        colval[gbase + i] = make_int2(0, 0);
}

// ================= gather SpMM (fp16), 8 lanes/row, LDS-staged colval ======
__device__ __forceinline__ void fma_slice(__half2& ac0, __half2& ac1,
        __half2& ac2, __half2& ac3, int cy, uint4 x) {
    __half2 vv = bits2h2(cy);
    ac0 = __hfma2(vv, bits2h2((int)x.x), ac0);
    ac1 = __hfma2(vv, bits2h2((int)x.y), ac1);
    ac2 = __hfma2(vv, bits2h2((int)x.z), ac2);
    ac3 = __hfma2(vv, bits2h2((int)x.w), ac3);
}

template <bool USE_LDS>
__device__ __forceinline__ void ldk(int kk, int kel, int l, int beg0,
        const int2* __restrict__ gcv, const int2* lcv,
        const uint4* __restrict__ tab, int2& cv, uint4& xv) {
    int kc = min(kk, kel);
    cv = USE_LDS ? lcv[kc - beg0] : gcv[kc];
    if (kk > kel) cv.y = 0;
    xv = tab[(((unsigned)cv.x) << 3) + l];
}

// 4-deep pipelined accumulation (R10 best-measured; depth-6 null in R12).
template <bool USE_LDS>
__device__ __forceinline__ void row_accum(
        int lo, int hi, int l, int beg0,
        const int2* __restrict__ gcv, const int2* lcv,
        const uint4* __restrict__ tab,
        __half2& ac0, __half2& ac1, __half2& ac2, __half2& ac3) {
    if (hi <= lo) return;
    const int kel = hi - 1;
    int2 c0, c1, c2, c3; uint4 x0, x1, x2, x3;
    ldk<USE_LDS>(lo,     kel, l, beg0, gcv, lcv, tab, c0, x0);
    ldk<USE_LDS>(lo + 1, kel, l, beg0, gcv, lcv, tab, c1, x1);
    ldk<USE_LDS>(lo + 2, kel, l, beg0, gcv, lcv, tab, c2, x2);
    ldk<USE_LDS>(lo + 3, kel, l, beg0, gcv, lcv, tab, c3, x3);
    for (int kk = lo + 4; kk < hi; kk += 4) {
        int2 d0, d1, d2, d3; uint4 y0, y1, y2, y3;
        ldk<USE_LDS>(kk,     kel, l, beg0, gcv, lcv, tab, d0, y0);
        ldk<USE_LDS>(kk + 1, kel, l, beg0, gcv, lcv, tab, d1, y1);
        ldk<USE_LDS>(kk + 2, kel, l, beg0, gcv, lcv, tab, d2, y2);
        ldk<USE_LDS>(kk + 3, kel, l, beg0, gcv, lcv, tab, d3, y3);
        fma_slice(ac0, ac1, ac2, ac3, c0.y, x0);
        fma_slice(ac0, ac1, ac2, ac3, c1.y, x1);
        fma_slice(ac0, ac1, ac2, ac3, c2.y, x2);
        fma_slice(ac0, ac1, ac2, ac3, c3.y, x3);
        c0 = d0; x0 = y0; c1 = d1; x1 = y1;
        c2 = d2; x2 = y2; c3 = d3; x3 = y3;
    }
    fma_slice(ac0, ac1, ac2, ac3, c0.y, x0);
    fma_slice(ac0, ac1, ac2, ac3, c1.y, x1);
    fma_slice(ac0, ac1, ac2, ac3, c2.y, x2);
    fma_slice(ac0, ac1, ac2, ac3, c3.y, x3);
}

__global__ __launch_bounds__(256) void spmm_csr(
        const int* __restrict__ rowptr, const int2* __restrict__ colval,
        const unsigned short* __restrict__ h_cur, unsigned short* __restrict__ h_next) {
    __shared__ int2 ecv[SLDS];
    const int t = threadIdx.x;
    const int g = t >> 3;            // row group 0..31
    const int l = t & 7;             // uint4 slice within row
    const int base = blockIdx.x * SROWS;
    const int r = base + g;
    int lo = 0, hi = 0;
    if (r < N_NODES) { lo = rowptr[r]; hi = rowptr[r + 1]; }
    const int beg0 = rowptr[base];
    const int end0 = rowptr[min(base + SROWS, N_NODES)];
    const int nE = end0 - beg0;
    const bool use_lds = (nE <= SLDS);
    if (use_lds)
        for (int i = t; i < nE; i += 256) ecv[i] = colval[beg0 + i];
    __syncthreads();
    __half2 ac0 = __float2half2_rn(0.0f), ac1 = ac0, ac2 = ac0, ac3 = ac0;
    const uint4* tab = (const uint4*)h_cur;
    if (r < N_NODES) {
        if (use_lds)
            row_accum<true>(lo, hi, l, beg0, colval, ecv, tab, ac0, ac1, ac2, ac3);
        else
            row_accum<false>(lo, hi, l, beg0, colval, ecv, tab, ac0, ac1, ac2, ac3);
        ((uint4*)(h_next + (size_t)r * EMB))[l] =
            make_uint4((unsigned)h22bits(ac0), (unsigned)h22bits(ac1),
                       (unsigned)h22bits(ac2), (unsigned)h22bits(ac3));
    }
}

// ---- gather one row (spmm_sel inner loop, exact arithmetic), all-lane result
__device__ __forceinline__ void gather_row(
        const int* __restrict__ rowptr, const int2* __restrict__ colval,
        const unsigned short* __restrict__ h_cur, int r, int g, int l,
        int& ra0, int& ra1, int& ra2, int& ra3) {
    const int beg = rowptr[r], end = rowptr[r + 1];
    __half2 ac0 = __float2half2_rn(0.0f), ac1 = ac0, ac2 = ac0, ac3 = ac0;
    int e = beg + g;
    if (e < end) {
        int2 cv = colval[e];
        uint4 x = ((const uint4*)(h_cur + (size_t)cv.x * EMB))[l];
        e += 8;
        if (e < end) {
            int2 cv2 = colval[e];
            uint4 x2 = ((const uint4*)(h_cur + (size_t)cv2.x * EMB))[l];
            for (e += 8; e < end; e += 8) {
                int2 cv3 = colval[e];
                uint4 x3 = ((const uint4*)(h_cur + (size_t)cv3.x * EMB))[l];
                fma_slice(ac0, ac1, ac2, ac3, cv.y, x);
                cv = cv2; x = x2; cv2 = cv3; x2 = x3;
            }
            fma_slice(ac0, ac1, ac2, ac3, cv.y, x);
            cv = cv2; x = x2;
        }
        fma_slice(ac0, ac1, ac2, ac3, cv.y, x);
    }
    int a0 = h22bits(ac0), a1 = h22bits(ac1), a2 = h22bits(ac2), a3 = h22bits(ac3);
    #pragma unroll
    for (int m = 8; m < 64; m <<= 1) {
        a0 = h22bits(__hadd2(bits2h2(a0), bits2h2(__shfl_xor(a0, m, 64))));
        a1 = h22bits(__hadd2(bits2h2(a1), bits2h2(__shfl_xor(a1, m, 64))));
        a2 = h22bits(__hadd2(bits2h2(a2), bits2h2(__shfl_xor(a2, m, 64))));
        a3 = h22bits(__hadd2(bits2h2(a3), bits2h2(__shfl_xor(a3, m, 64))));
    }
    ra0 = a0; ra1 = a1; ra2 = a2; ra3 = a3;
}

// store layer3 row + e2 self row (f32) into LDS slice [64]
__device__ __forceinline__ void store_row(float* dst,
        const unsigned short* __restrict__ h_cur, int r, int l,
        int a0, int a1, int a2, int a3) {
    uint4 hx = ((const uint4*)(h_cur + (size_t)r * EMB))[l];
    float2 f0 = __half22float2(bits2h2(a0));
    float2 f1 = __half22float2(bits2h2(a1));
    float2 f2 = __half22float2(bits2h2(a2));
    float2 f3 = __half22float2(bits2h2(a3));
    float2 s0 = __half22float2(bits2h2((int)hx.x));
    float2 s1 = __half22float2(bits2h2((int)hx.y));
    float2 s2 = __half22float2(bits2h2((int)hx.z));
    float2 s3 = __half22float2(bits2h2((int)hx.w));
    float* d = dst + 8 * l;
    d[0] = f0.x + s0.x; d[1] = f0.y + s0.y; d[2] = f1.x + s1.x; d[3] = f1.y + s1.y;
    d[4] = f2.x + s2.x; d[5] = f2.y + s2.y; d[6] = f3.x + s3.x; d[7] = f3.y + s3.y;
}

// ======== sel_loss: layer-3 selective SpMM fused with the batch losses ======
__global__ __launch_bounds__(256) void sel_loss(
        const int* __restrict__ rowptr, const int2* __restrict__ colval,
        const int* __restrict__ user, const int* __restrict__ pos,
        const int* __restrict__ neg,
        const float* __restrict__ uw, const float* __restrict__ iw,
        const unsigned short* __restrict__ hA,   // layer-2 table (gather + self)
        const unsigned short* __restrict__ hB,   // layer-1 table (e1 term)
        unsigned short* __restrict__ unh, unsigned short* __restrict__ pnh,
        float* __restrict__ diag,
        float* __restrict__ pbpr, float* __restrict__ preg) {
    __shared__ float srow[3][4][64];
    __shared__ float lb[4], lr[4];
    const int t = threadIdx.x;
    const int lane = t & 63;
    const int w = t >> 6;
    const int g = lane >> 3, l = lane & 7;
    const int b = blockIdx.x * 4 + w;
    const int nu = user[b], np = pos[b], ng = neg[b];
    int a0, a1, a2, a3;
    gather_row(rowptr, colval, hA, nu, g, l, a0, a1, a2, a3);
    if (g == 0) store_row(&srow[0][w][0], hA, nu, l, a0, a1, a2, a3);
    gather_row(rowptr, colval, hA, NUM_USERS + np, g, l, a0, a1, a2, a3);
    if (g == 0) store_row(&srow[1][w][0], hA, NUM_USERS + np, l, a0, a1, a2, a3);
    gather_row(rowptr, colval, hA, NUM_USERS + ng, g, l, a0, a1, a2, a3);
    if (g == 0) store_row(&srow[2][w][0], hA, NUM_USERS + ng, l, a0, a1, a2, a3);
    __syncthreads();
    const float inv4 = 0.25f;  // / (GCN_LAYERS + 1)
    float u = (uw[(size_t)nu * EMB + lane]
             + h2f(hB[(size_t)nu * EMB + lane])
             + srow[0][w][lane]) * inv4;
    float p = (iw[(size_t)np * EMB + lane]
             + h2f(hB[(size_t)(NUM_USERS + np) * EMB + lane])
             + srow[1][w][lane]) * inv4;
    float n = (iw[(size_t)ng * EMB + lane]
             + h2f(hB[(size_t)(NUM_USERS + ng) * EMB + lane])
             + srow[2][w][lane]) * inv4;
    float pos_s = wave_sum(u * p);
    float neg_s = wave_sum(u * n);
    float uu = wave_sum(u * u);
    float pp = wave_sum(p * p);
    float nn = wave_sum(n * n);
    float ru = rsqrtf(uu), rp = rsqrtf(pp);
    unh[(size_t)b * EMB + lane] = f2h_bits(u * ru);
    pnh[(size_t)b * EMB + lane] = f2h_bits(p * rp);
    if (lane == 0) {
        diag[b] = pos_s * ru * rp * (1.0f / TAU);
        float d = pos_s - neg_s;
        float tt = -d;
        lb[w] = fmaxf(tt, 0.0f) + log1pf(expf(-fabsf(tt)));  // softplus(-d)
        lr[w] = uu + pp + nn;
    }
    __syncthreads();
    if (t == 0) {
        pbpr[blockIdx.x] = lb[0] + lb[1] + lb[2] + lb[3];
        preg[blockIdx.x] = lr[0] + lr[1] + lr[2] + lr[3];
    }
}

// ================= SSL via MFMA (16x16x32 f16, fp32 accum) =================
__global__ __launch_bounds__(256) void ssl_mfma(
        const unsigned short* __restrict__ unh, const unsigned short* __restrict__ pnh,
        float* __restrict__ rowsum_p) {
    const int t = threadIdx.x;
    const int lane = t & 63;
    const int idx = lane & 15, quad = lane >> 4;
    int job = blockIdx.x * 4 + (t >> 6);     // 4096 jobs = 256 it x 16 js
    int it = job & 255, js = job >> 8;
    const int i0 = it * 16;
    half8 a0 = *(const half8*)(unh + (size_t)(i0 + idx) * EMB + quad * 8);
    half8 a1 = *(const half8*)(unh + (size_t)(i0 + idx) * EMB + 32 + quad * 8);
    float rs0 = 0.0f, rs1 = 0.0f, rs2 = 0.0f, rs3 = 0.0f;
    const int NJT = BATCH / JSPLIT / 16;     // 16
    for (int jt = 0; jt < NJT; jt++) {
        int j0 = js * (BATCH / JSPLIT) + jt * 16;
        half8 b0 = *(const half8*)(pnh + (size_t)(j0 + idx) * EMB + quad * 8);
        half8 b1 = *(const half8*)(pnh + (size_t)(j0 + idx) * EMB + 32 + quad * 8);
        f32x4 c = {0.0f, 0.0f, 0.0f, 0.0f};
        c = __builtin_amdgcn_mfma_f32_16x16x32_f16(a0, b0, c, 0, 0, 0);
        c = __builtin_amdgcn_mfma_f32_16x16x32_f16(a1, b1, c, 0, 0, 0);
        rs0 += __expf(c[0] * (1.0f / TAU));
        rs1 += __expf(c[1] * (1.0f / TAU));
        rs2 += __expf(c[2] * (1.0f / TAU));
        rs3 += __expf(c[3] * (1.0f / TAU));
    }
    #pragma unroll
    for (int m = 1; m < 16; m <<= 1) {
        rs0 += __shfl_xor(rs0, m, 64);
        rs1 += __shfl_xor(rs1, m, 64);
        rs2 += __shfl_xor(rs2, m, 64);
        rs3 += __shfl_xor(rs3, m, 64);
    }
    if (idx == 0) {
        float* dst = rowsum_p + (size_t)js * BATCH + i0 + quad * 4;
        dst[0] = rs0; dst[1] = rs1; dst[2] = rs2; dst[3] = rs3;
    }
}

// single block: reduce rowsum partials + ssl terms + bpr/reg partials -> loss
__global__ __launch_bounds__(256) void finalize(
        const float* __restrict__ rowsum_p, const float* __restrict__ diag,
        const float* __restrict__ pbpr, const float* __restrict__ preg,
        float* __restrict__ out) {
    __shared__ float red[3][4];
    const int t = threadIdx.x;
    float sb = 0.0f, sr = 0.0f, ss = 0.0f;
    for (int i = t; i < BATCH / 4; i += 256) { sb += pbpr[i]; sr += preg[i]; }
    for (int i = t; i < BATCH; i += 256) {
        float rs = 0.0f;
        #pragma unroll
        for (int j = 0; j < JSPLIT; j++) rs += rowsum_p[(size_t)j * BATCH + i];
        ss += logf(rs) - diag[i];
    }
    sb = wave_sum(sb); sr = wave_sum(sr); ss = wave_sum(ss);
    const int w = t >> 6;
    if ((t & 63) == 0) { red[0][w] = sb; red[1][w] = sr; red[2][w] = ss; }
    __syncthreads();
    if (t == 0) {
        float bpr_sum = red[0][0] + red[0][1] + red[0][2] + red[0][3];
        float reg_sum = red[1][0] + red[1][1] + red[1][2] + red[1][3];
        float ssl_sum = red[2][0] + red[2][1] + red[2][2] + red[2][3];
        float bpr = bpr_sum * (1.0f / BATCH);
        float reg = 0.5f * reg_sum * (1.0f / BATCH) * REG_LAMBDA;
        float ssl = ssl_sum * (1.0f / BATCH) * SSL_LAMBDA;
        out[0] = bpr + reg + ssl;
    }
}

extern "C" void kernel_launch(void* const* d_in, const int* in_sizes, int n_in,
                              void* d_out, int out_size, void* d_ws, size_t ws_size,
                              hipStream_t stream) {
    const int*   user    = (const int*)d_in[0];
    const int*   pos     = (const int*)d_in[1];
    const int*   neg     = (const int*)d_in[2];
    const int*   adj_row = (const int*)d_in[3];
    const int*   adj_col = (const int*)d_in[4];
    const float* adj_val = (const float*)d_in[5];
    const float* user_w  = (const float*)d_in[6];
    const float* item_w  = (const float*)d_in[7];
    float* out = (float*)d_out;

    // ---- workspace layout ----
    unsigned short* hA = (unsigned short*)d_ws;            // fp16 table (19.2 MB)
    unsigned short* hB = hA + (size_t)N_NODES * EMB;       // fp16 table (19.2 MB)
    float* buf1   = (float*)d_ws + (size_t)N_NODES * EMB;  // 38.4 MB arena region
    float* sel    = buf1 + (size_t)N_NODES * EMB;          // (unused, layout keep)
    unsigned short* unh = (unsigned short*)(sel + (size_t)3 * BATCH * EMB); // 512KB
    unsigned short* pnh = unh + (size_t)BATCH * EMB;       // 512 KB
    float* diag   = (float*)(pnh + (size_t)BATCH * EMB);   // 4096 f
    float* rowsum_p = diag + BATCH;                        // 16*4096 f
    float* pbpr   = rowsum_p + JSPLIT * BATCH;             // 1024 f
    float* preg   = pbpr + 1024;                           // 1024 f
    int*   rowptr = (int*)(preg + 1024);                   // 150016 i
    int*   bucket_cursor = rowptr + 150016;                // 512 i
    int*   bucket_base   = bucket_cursor + 512;            // 512 i (layout pad)
    int2*  colval = (int2*)(bucket_base + 512);            // 2.4M int2 (19.2 MB)
    int2*  arena  = (int2*)buf1;  // NB*CAP int2 = 31.95 MB <= 38.4 MB region

    // zero bucket cursors (2 KB), then fused cast + binned scatter (1024 thr)
    (void)hipMemsetAsync(bucket_cursor, 0, 512 * sizeof(int), stream);
    prep<<<BINA_BLK + CAST_BLK, dim3(1024), 0, stream>>>(adj_row, adj_col, adj_val,
                                                         bucket_cursor, arena,
                                                         (const float4*)user_w,
                                                         (const float4*)item_w,
                                                         (uint2*)hA);
    bin_sort<<<NB, dim3(1024), 0, stream>>>(bucket_cursor, arena, rowptr, colval);

    dim3 blk(256);
    // layers 1,2: full spmm (fp16 tables)
    spmm_csr<<<(N_NODES + SROWS - 1) / SROWS, blk, 0, stream>>>(rowptr, colval, hA, hB);
    spmm_csr<<<(N_NODES + SROWS - 1) / SROWS, blk, 0, stream>>>(rowptr, colval, hB, hA);

    // layer-3 selective spmm + e2 self + e0/e1 gathers + losses (fused)
    sel_loss<<<BATCH / 4, blk, 0, stream>>>(rowptr, colval, user, pos, neg,
                                            user_w, item_w, hA, hB,
                                            unh, pnh, diag, pbpr, preg);
    // ssl rowsums, then tiny finalize (kernel boundary = cheap global sync)
    ssl_mfma<<<BATCH * JSPLIT / 16 / 4, blk, 0, stream>>>(unh, pnh, rowsum_p);
    finalize<<<1, blk, 0, stream>>>(rowsum_p, diag, pbpr, preg, out);
}